// Round 1
// 339.195 us; speedup vs baseline: 1.1558x; 1.1558x over previous
//
#include <hip/hip_runtime.h>
#include <stdint.h>

#define T_TOK 1024
#define H_DIM 1024
#define I_DIM 2816
#define E_NUM 8
#define KSPLIT 4
#define K2_STEPS (I_DIM / 64 / KSPLIT)   // 11 K-steps of 64 per split

typedef __attribute__((ext_vector_type(8))) short bf16x8;
typedef __attribute__((ext_vector_type(4))) float f32x4;

struct Meta { int counts[E_NUM]; int tiles[E_NUM]; int offs[E_NUM]; };

__device__ __forceinline__ unsigned short f2b(float f) {
    unsigned u = __float_as_uint(f);
    u += 0x7fffu + ((u >> 16) & 1u);   // round-to-nearest-even
    return (unsigned short)(u >> 16);
}

__device__ __forceinline__ uint4 pack8(const float4 a, const float4 b) {
    union { unsigned short us[8]; uint4 v; } u;
    u.us[0] = f2b(a.x); u.us[1] = f2b(a.y); u.us[2] = f2b(a.z); u.us[3] = f2b(a.w);
    u.us[4] = f2b(b.x); u.us[5] = f2b(b.y); u.us[6] = f2b(b.z); u.us[7] = f2b(b.w);
    return u.v;
}

// ---------------- routing: softmax -> top2 -> renorm -> grouped token lists ----------------
__global__ void route_kernel(const float* __restrict__ logits,
                             int* __restrict__ tok, float* __restrict__ gate,
                             Meta* __restrict__ meta) {
    __shared__ int cnt[E_NUM];
    const int tid = threadIdx.x;   // == token id, blockDim=1024
    if (tid < E_NUM) cnt[tid] = 0;
    for (int j = tid; j < E_NUM * T_TOK; j += 1024) { tok[j] = 0; gate[j] = 0.f; }
    __syncthreads();

    float p[E_NUM];
    const float* lrow = logits + tid * E_NUM;
    float m = -1e30f;
    #pragma unroll
    for (int e = 0; e < E_NUM; ++e) { p[e] = lrow[e]; m = fmaxf(m, p[e]); }
    #pragma unroll
    for (int e = 0; e < E_NUM; ++e) p[e] = __expf(p[e] - m);
    int e0 = 0; float v0 = p[0];
    #pragma unroll
    for (int e = 1; e < E_NUM; ++e) if (p[e] > v0) { v0 = p[e]; e0 = e; }
    int e1 = -1; float v1 = -1.f;
    #pragma unroll
    for (int e = 0; e < E_NUM; ++e) if (e != e0 && p[e] > v1) { v1 = p[e]; e1 = e; }
    const float inv = 1.f / (v0 + v1);       // softmax denom cancels in ratio
    const float g0 = v0 * inv, g1 = v1 * inv;

    const int p0 = atomicAdd(&cnt[e0], 1);
    const int p1 = atomicAdd(&cnt[e1], 1);
    tok[e0 * T_TOK + p0] = tid; gate[e0 * T_TOK + p0] = g0;
    tok[e1 * T_TOK + p1] = tid; gate[e1 * T_TOK + p1] = g1;
    __syncthreads();
    if (tid == 0) {
        int off = 0;
        for (int e = 0; e < E_NUM; ++e) {
            const int c = cnt[e];
            const int t = (c + 127) >> 7;
            meta->counts[e] = c; meta->tiles[e] = t; meta->offs[e] = off;
            off += t * 128;
        }
    }
}

// ---------------- x fp32 -> bf16 ----------------
__global__ void cvt_x_kernel(const float* __restrict__ x, unsigned short* __restrict__ xb) {
    const int i = blockIdx.x * blockDim.x + threadIdx.x;
    const float4 v = ((const float4*)x)[i];
    ushort4 o; o.x = f2b(v.x); o.y = f2b(v.y); o.z = f2b(v.z); o.w = f2b(v.w);
    ((ushort4*)xb)[i] = o;
}

// ---------------- GEMM1: act = silu(x@w1^T) * (x@w3^T), grouped per expert ----------------
// grid: (I/64, E, maxMTiles), block 512 (8 waves). Tile: 128 tokens x 64 I-cols, BK=64.
// LDS tiles XOR-swizzled: ushort col ^= (row&7)<<3  (16B-granular, kills frag-read conflicts)
__launch_bounds__(512)
__global__ void gemm1_kernel(const unsigned short* __restrict__ xb,
                             const float* __restrict__ w1,
                             const float* __restrict__ w3,
                             const int* __restrict__ tok,
                             const Meta* __restrict__ meta,
                             unsigned short* __restrict__ act) {
    const int e = blockIdx.y;
    const int mt = blockIdx.z;
    if (mt >= meta->tiles[e]) return;
    const int it = blockIdx.x;
    const int tid = threadIdx.x;

    __shared__ __align__(16) unsigned short As[128 * 64];   // 16 KB
    __shared__ __align__(16) unsigned short B1s[64 * 64];   // 8 KB
    __shared__ __align__(16) unsigned short B3s[64 * 64];   // 8 KB

    // ---- staging assignment: row = tid>>3 (0..63), 8-elem chunk = tid&7 ----
    const int srow = tid >> 3, ssub = tid & 7;
    const int t0 = tok[e * T_TOK + mt * 128 + srow];
    const int t1 = tok[e * T_TOK + mt * 128 + 64 + srow];
    const unsigned short* ap0 = xb + (size_t)t0 * H_DIM + ssub * 8;
    const unsigned short* ap1 = xb + (size_t)t1 * H_DIM + ssub * 8;
    const int scol = (ssub * 8) ^ ((srow & 7) << 3);
    unsigned short* al0 = &As[srow * 64 + scol];
    unsigned short* al1 = &As[(64 + srow) * 64 + scol];   // (64+srow)&7 == srow&7

    const size_t wbase = (size_t)e * I_DIM * H_DIM + (size_t)(it * 64 + srow) * H_DIM + ssub * 8;
    const float* b1p = w1 + wbase;
    const float* b3p = w3 + wbase;
    unsigned short* bl1 = &B1s[srow * 64 + scol];
    unsigned short* bl3 = &B3s[srow * 64 + scol];

    // ---- wave decomposition: 8 waves = 4(M) x 2(N), each 32x32 output ----
    const int wave = tid >> 6, lane = tid & 63;
    const int quad = lane >> 4, l15 = lane & 15;
    const int mbase = (wave >> 1) * 32;
    const int nbase = (wave & 1) * 32;

    f32x4 acc1[2][2], acc3[2][2];
    #pragma unroll
    for (int m = 0; m < 2; ++m)
        #pragma unroll
        for (int n = 0; n < 2; ++n) {
            acc1[m][n] = (f32x4){0.f, 0.f, 0.f, 0.f};
            acc3[m][n] = (f32x4){0.f, 0.f, 0.f, 0.f};
        }

    // register-double-buffered staging
    uint4 ra0 = *(const uint4*)ap0, ra1 = *(const uint4*)ap1;
    float4 rb1a = *(const float4*)b1p, rb1b = *(const float4*)(b1p + 4);
    float4 rb3a = *(const float4*)b3p, rb3b = *(const float4*)(b3p + 4);

    const int NK = H_DIM / 64;   // 16
    for (int ks = 0; ks < NK; ++ks) {
        __syncthreads();
        *(uint4*)al0 = ra0;
        *(uint4*)al1 = ra1;
        *(uint4*)bl1 = pack8(rb1a, rb1b);
        *(uint4*)bl3 = pack8(rb3a, rb3b);
        __syncthreads();
        if (ks + 1 < NK) {
            const int k0 = (ks + 1) * 64;
            ra0 = *(const uint4*)(ap0 + k0);  ra1 = *(const uint4*)(ap1 + k0);
            rb1a = *(const float4*)(b1p + k0); rb1b = *(const float4*)(b1p + k0 + 4);
            rb3a = *(const float4*)(b3p + k0); rb3b = *(const float4*)(b3p + k0 + 4);
        }
        bf16x8 a[2][2], bf1[2][2], bf3[2][2];
        #pragma unroll
        for (int m = 0; m < 2; ++m) {
            const int row = mbase + m * 16 + l15;
            #pragma unroll
            for (int kk = 0; kk < 2; ++kk)
                a[m][kk] = *(const bf16x8*)&As[row * 64 + ((kk * 32 + quad * 8) ^ ((row & 7) << 3))];
        }
        #pragma unroll
        for (int n = 0; n < 2; ++n) {
            const int row = nbase + n * 16 + l15;
            #pragma unroll
            for (int kk = 0; kk < 2; ++kk) {
                const int off = row * 64 + ((kk * 32 + quad * 8) ^ ((row & 7) << 3));
                bf1[n][kk] = *(const bf16x8*)&B1s[off];
                bf3[n][kk] = *(const bf16x8*)&B3s[off];
            }
        }
        #pragma unroll
        for (int m = 0; m < 2; ++m)
            #pragma unroll
            for (int n = 0; n < 2; ++n)
                #pragma unroll
                for (int kk = 0; kk < 2; ++kk) {
                    acc1[m][n] = __builtin_amdgcn_mfma_f32_16x16x32_bf16(a[m][kk], bf1[n][kk], acc1[m][n], 0, 0, 0);
                    acc3[m][n] = __builtin_amdgcn_mfma_f32_16x16x32_bf16(a[m][kk], bf3[n][kk], acc3[m][n], 0, 0, 0);
                }
    }

    // epilogue: silu(h1)*h3 -> act (bf16). C/D layout: row=quad*4+reg, col=lane&15 (m89-verified)
    const int opad = meta->offs[e];
    #pragma unroll
    for (int m = 0; m < 2; ++m)
        #pragma unroll
        for (int n = 0; n < 2; ++n)
            #pragma unroll
            for (int rr = 0; rr < 4; ++rr) {
                const float v1 = acc1[m][n][rr];
                const float v3 = acc3[m][n][rr];
                const float s = v1 / (1.f + __expf(-v1)) * v3;
                const int row = opad + mt * 128 + mbase + m * 16 + quad * 4 + rr;
                const int col = it * 64 + nbase + n * 16 + l15;
                act[(size_t)row * I_DIM + col] = f2b(s);
            }
}

// ---------------- GEMM2: y = act @ w2^T, split-K x4, gate-scaled atomic scatter ----------------
// grid: (H/64, E, maxMTiles*KSPLIT), block 512. Tile: 128 rows x 64 H-cols, BK=64, 11 K-steps/split.
__launch_bounds__(512)
__global__ void gemm2_kernel(const unsigned short* __restrict__ act,
                             const float* __restrict__ w2,
                             const int* __restrict__ tok,
                             const float* __restrict__ gate,
                             const Meta* __restrict__ meta,
                             float* __restrict__ out) {
    const int e = blockIdx.y;
    const int mt = blockIdx.z >> 2;     // KSPLIT == 4
    const int kb = blockIdx.z & 3;
    if (mt >= meta->tiles[e]) return;
    const int it = blockIdx.x;
    const int tid = threadIdx.x;
    const int opad = meta->offs[e];

    __shared__ __align__(16) unsigned short As[128 * 64];   // 16 KB
    __shared__ __align__(16) unsigned short Bs[64 * 64];    // 8 KB

    const int srow = tid >> 3, ssub = tid & 7;
    const int kbase = kb * (K2_STEPS * 64);                 // kb*704
    const unsigned short* ap0 = act + (size_t)(opad + mt * 128 + srow) * I_DIM + kbase + ssub * 8;
    const unsigned short* ap1 = ap0 + (size_t)64 * I_DIM;
    const int scol = (ssub * 8) ^ ((srow & 7) << 3);
    unsigned short* al0 = &As[srow * 64 + scol];
    unsigned short* al1 = &As[(64 + srow) * 64 + scol];

    const float* bp = w2 + (size_t)e * H_DIM * I_DIM + (size_t)(it * 64 + srow) * I_DIM + kbase + ssub * 8;
    unsigned short* bl = &Bs[srow * 64 + scol];

    const int wave = tid >> 6, lane = tid & 63;
    const int quad = lane >> 4, l15 = lane & 15;
    const int mbase = (wave >> 1) * 32;
    const int nbase = (wave & 1) * 32;

    f32x4 acc[2][2];
    #pragma unroll
    for (int m = 0; m < 2; ++m)
        #pragma unroll
        for (int n = 0; n < 2; ++n) acc[m][n] = (f32x4){0.f, 0.f, 0.f, 0.f};

    uint4 ra0 = *(const uint4*)ap0, ra1 = *(const uint4*)ap1;
    float4 rba = *(const float4*)bp, rbb = *(const float4*)(bp + 4);

    for (int ks = 0; ks < K2_STEPS; ++ks) {
        __syncthreads();
        *(uint4*)al0 = ra0;
        *(uint4*)al1 = ra1;
        *(uint4*)bl = pack8(rba, rbb);
        __syncthreads();
        if (ks + 1 < K2_STEPS) {
            const int k0 = (ks + 1) * 64;
            ra0 = *(const uint4*)(ap0 + k0); ra1 = *(const uint4*)(ap1 + k0);
            rba = *(const float4*)(bp + k0); rbb = *(const float4*)(bp + k0 + 4);
        }
        bf16x8 a[2][2], bf[2][2];
        #pragma unroll
        for (int m = 0; m < 2; ++m) {
            const int row = mbase + m * 16 + l15;
            #pragma unroll
            for (int kk = 0; kk < 2; ++kk)
                a[m][kk] = *(const bf16x8*)&As[row * 64 + ((kk * 32 + quad * 8) ^ ((row & 7) << 3))];
        }
        #pragma unroll
        for (int n = 0; n < 2; ++n) {
            const int row = nbase + n * 16 + l15;
            #pragma unroll
            for (int kk = 0; kk < 2; ++kk)
                bf[n][kk] = *(const bf16x8*)&Bs[row * 64 + ((kk * 32 + quad * 8) ^ ((row & 7) << 3))];
        }
        #pragma unroll
        for (int m = 0; m < 2; ++m)
            #pragma unroll
            for (int n = 0; n < 2; ++n)
                #pragma unroll
                for (int kk = 0; kk < 2; ++kk)
                    acc[m][n] = __builtin_amdgcn_mfma_f32_16x16x32_bf16(a[m][kk], bf[n][kk], acc[m][n], 0, 0, 0);
    }

    // epilogue: out[token][col] += gate * partial_y ; skip padded rows (gate==0) to avoid
    // same-address atomic storms on token 0
    #pragma unroll
    for (int m = 0; m < 2; ++m)
        #pragma unroll
        for (int rr = 0; rr < 4; ++rr) {
            const int r = mt * 128 + mbase + m * 16 + quad * 4 + rr;
            const int t = tok[e * T_TOK + r];
            const float g = gate[e * T_TOK + r];
            if (g != 0.f) {
                #pragma unroll
                for (int n = 0; n < 2; ++n) {
                    const int col = it * 64 + nbase + n * 16 + l15;
                    atomicAdd(&out[(size_t)t * H_DIM + col], g * acc[m][n][rr]);
                }
            }
        }
}

extern "C" void kernel_launch(void* const* d_in, const int* in_sizes, int n_in,
                              void* d_out, int out_size, void* d_ws, size_t ws_size,
                              hipStream_t stream) {
    const float* x      = (const float*)d_in[0];
    const float* logits = (const float*)d_in[1];
    const float* w1     = (const float*)d_in[2];
    const float* w3     = (const float*)d_in[3];
    const float* w2     = (const float*)d_in[4];
    float* out = (float*)d_out;

    char* ws = (char*)d_ws;
    int*   tok  = (int*)ws;                                   // 8*1024 ints   (32 KB)
    float* gate = (float*)(ws + 32768);                       // 8*1024 floats (32 KB)
    Meta*  meta = (Meta*)(ws + 65536);
    unsigned short* xb  = (unsigned short*)(ws + 131072);     // 1M bf16 (2 MB)
    unsigned short* act = (unsigned short*)(ws + 131072 + 2097152); // <=3072 x 2816 bf16 (~16.5 MB)

    hipMemsetAsync(d_out, 0, (size_t)T_TOK * H_DIM * sizeof(float), stream);
    route_kernel<<<1, 1024, 0, stream>>>(logits, tok, gate, meta);
    cvt_x_kernel<<<T_TOK * H_DIM / 4 / 256, 256, 0, stream>>>(x, xb);
    gemm1_kernel<<<dim3(I_DIM / 64, E_NUM, 8), 512, 0, stream>>>(xb, w1, w3, tok, meta, act);
    gemm2_kernel<<<dim3(H_DIM / 64, E_NUM, 8 * KSPLIT), 512, 0, stream>>>(act, w2, tok, gate, meta, out);
}

// Round 2
// 332.465 us; speedup vs baseline: 1.1792x; 1.0202x over previous
//
#include <hip/hip_runtime.h>
#include <stdint.h>

#define T_TOK 1024
#define H_DIM 1024
#define I_DIM 2816
#define E_NUM 8
#define KSPLIT 2
#define K2_STEPS (I_DIM / 64 / KSPLIT)   // 22 K-steps of 64 per split
#define MAXROWS 3072                     // worst-case padded rows (sum ceil <= 2048/128 + 8 tiles)

typedef __attribute__((ext_vector_type(8))) short bf16x8;
typedef __attribute__((ext_vector_type(4))) float f32x4;

struct Meta { int counts[E_NUM]; int tiles[E_NUM]; int offs[E_NUM]; };

__device__ __forceinline__ unsigned short f2b(float f) {
    unsigned u = __float_as_uint(f);
    u += 0x7fffu + ((u >> 16) & 1u);   // round-to-nearest-even
    return (unsigned short)(u >> 16);
}

__device__ __forceinline__ uint4 pack8(const float4 a, const float4 b) {
    union { unsigned short us[8]; uint4 v; } u;
    u.us[0] = f2b(a.x); u.us[1] = f2b(a.y); u.us[2] = f2b(a.z); u.us[3] = f2b(a.w);
    u.us[4] = f2b(b.x); u.us[5] = f2b(b.y); u.us[6] = f2b(b.z); u.us[7] = f2b(b.w);
    return u.v;
}

// raw barrier: make our LDS writes/reads visible WITHOUT draining vmcnt (keeps global
// loads in flight across the barrier — the counted-vmcnt pipeline, m201/T3-T4 pattern)
#define SYNC_RAW() do { asm volatile("s_waitcnt lgkmcnt(0)" ::: "memory"); __builtin_amdgcn_s_barrier(); } while (0)

// ---------------- routing: softmax -> top2 -> renorm -> grouped token lists ----------------
__global__ void route_kernel(const float* __restrict__ logits,
                             int* __restrict__ tok,
                             int4* __restrict__ comb,
                             Meta* __restrict__ meta) {
    __shared__ int cnt[E_NUM];
    __shared__ int soffs[E_NUM];
    const int tid = threadIdx.x;   // == token id, blockDim=1024
    if (tid < E_NUM) cnt[tid] = 0;
    for (int j = tid; j < E_NUM * T_TOK; j += 1024) tok[j] = 0;
    __syncthreads();

    float p[E_NUM];
    const float* lrow = logits + tid * E_NUM;
    float m = -1e30f;
    #pragma unroll
    for (int e = 0; e < E_NUM; ++e) { p[e] = lrow[e]; m = fmaxf(m, p[e]); }
    #pragma unroll
    for (int e = 0; e < E_NUM; ++e) p[e] = __expf(p[e] - m);
    int e0 = 0; float v0 = p[0];
    #pragma unroll
    for (int e = 1; e < E_NUM; ++e) if (p[e] > v0) { v0 = p[e]; e0 = e; }
    int e1 = -1; float v1 = -1.f;
    #pragma unroll
    for (int e = 0; e < E_NUM; ++e) if (e != e0 && p[e] > v1) { v1 = p[e]; e1 = e; }
    const float inv = 1.f / (v0 + v1);       // softmax denom cancels in ratio
    const float g0 = v0 * inv, g1 = v1 * inv;

    const int p0 = atomicAdd(&cnt[e0], 1);
    const int p1 = atomicAdd(&cnt[e1], 1);
    tok[e0 * T_TOK + p0] = tid;
    tok[e1 * T_TOK + p1] = tid;
    __syncthreads();
    if (tid == 0) {
        int off = 0;
        for (int e = 0; e < E_NUM; ++e) {
            const int c = cnt[e];
            const int t = (c + 127) >> 7;
            meta->counts[e] = c; meta->tiles[e] = t; meta->offs[e] = off;
            soffs[e] = off;
            off += t * 128;
        }
    }
    __syncthreads();
    // padded row indices of this token's two expert slots + gates
    comb[tid] = make_int4(soffs[e0] + p0, soffs[e1] + p1,
                          __float_as_int(g0), __float_as_int(g1));
}

// ---------------- x fp32 -> bf16 ----------------
__global__ void cvt_x_kernel(const float* __restrict__ x, unsigned short* __restrict__ xb) {
    const int i = blockIdx.x * blockDim.x + threadIdx.x;
    const float4 v = ((const float4*)x)[i];
    ushort4 o; o.x = f2b(v.x); o.y = f2b(v.y); o.z = f2b(v.z); o.w = f2b(v.w);
    ((ushort4*)xb)[i] = o;
}

// ---------------- GEMM1: act = silu(x@w1^T) * (x@w3^T), grouped per expert ----------------
// grid: (I/64, E, maxMTiles), block 512 (8 waves). Tile: 128 tokens x 64 I-cols, BK=64.
// LDS double-buffered (64 KB), ONE raw barrier per K-step, 2-deep register prefetch:
// a tile's global loads are issued ~2 K-step bodies before their LDS write (counted vmcnt).
// LDS tiles XOR-swizzled: ushort col ^= (row&7)<<3.
__launch_bounds__(512, 4)
__global__ void gemm1_kernel(const unsigned short* __restrict__ xb,
                             const float* __restrict__ w1,
                             const float* __restrict__ w3,
                             const int* __restrict__ tok,
                             const Meta* __restrict__ meta,
                             unsigned short* __restrict__ act) {
    const int e = blockIdx.y;
    const int mt = blockIdx.z;
    if (mt >= meta->tiles[e]) return;
    const int it = blockIdx.x;
    const int tid = threadIdx.x;

    __shared__ __align__(16) unsigned short As[2][128 * 64];   // 2 x 16 KB
    __shared__ __align__(16) unsigned short B1s[2][64 * 64];   // 2 x 8 KB
    __shared__ __align__(16) unsigned short B3s[2][64 * 64];   // 2 x 8 KB

    // ---- staging assignment: row = tid>>3 (0..63), 8-elem chunk = tid&7 ----
    const int srow = tid >> 3, ssub = tid & 7;
    const int t0 = tok[e * T_TOK + mt * 128 + srow];
    const int t1 = tok[e * T_TOK + mt * 128 + 64 + srow];
    const unsigned short* ap0 = xb + (size_t)t0 * H_DIM + ssub * 8;
    const unsigned short* ap1 = xb + (size_t)t1 * H_DIM + ssub * 8;
    const int scol = (ssub * 8) ^ ((srow & 7) << 3);
    const int aoff0 = srow * 64 + scol;
    const int aoff1 = (64 + srow) * 64 + scol;   // (64+srow)&7 == srow&7
    const int boff  = srow * 64 + scol;

    const size_t wbase = (size_t)e * I_DIM * H_DIM + (size_t)(it * 64 + srow) * H_DIM + ssub * 8;
    const float* b1p = w1 + wbase;
    const float* b3p = w3 + wbase;

    // ---- wave decomposition: 8 waves = 4(M) x 2(N), each 32x32 output ----
    const int wave = tid >> 6, lane = tid & 63;
    const int quad = lane >> 4, l15 = lane & 15;
    const int mbase = (wave >> 1) * 32;
    const int nbase = (wave & 1) * 32;

    f32x4 acc1[2][2], acc3[2][2];
    #pragma unroll
    for (int m = 0; m < 2; ++m)
        #pragma unroll
        for (int n = 0; n < 2; ++n) {
            acc1[m][n] = (f32x4){0.f, 0.f, 0.f, 0.f};
            acc3[m][n] = (f32x4){0.f, 0.f, 0.f, 0.f};
        }

#define G1_LOAD(S, koff) do { \
        S##_a0  = *(const uint4*)(ap0 + (koff));      S##_a1  = *(const uint4*)(ap1 + (koff)); \
        S##_b1a = *(const float4*)(b1p + (koff));     S##_b1b = *(const float4*)(b1p + (koff) + 4); \
        S##_b3a = *(const float4*)(b3p + (koff));     S##_b3b = *(const float4*)(b3p + (koff) + 4); \
    } while (0)

#define G1_STORE(S, B) do { \
        *(uint4*)&As[B][aoff0] = S##_a0; \
        *(uint4*)&As[B][aoff1] = S##_a1; \
        *(uint4*)&B1s[B][boff] = pack8(S##_b1a, S##_b1b); \
        *(uint4*)&B3s[B][boff] = pack8(S##_b3a, S##_b3b); \
    } while (0)

#define G1_COMPUTE(B) do { \
        bf16x8 afr[2][2], f1[2][2], f3[2][2]; \
        _Pragma("unroll") \
        for (int m = 0; m < 2; ++m) { \
            const int row = mbase + m * 16 + l15; \
            _Pragma("unroll") \
            for (int kk = 0; kk < 2; ++kk) \
                afr[m][kk] = *(const bf16x8*)&As[B][row * 64 + ((kk * 32 + quad * 8) ^ ((row & 7) << 3))]; \
        } \
        _Pragma("unroll") \
        for (int n = 0; n < 2; ++n) { \
            const int row = nbase + n * 16 + l15; \
            _Pragma("unroll") \
            for (int kk = 0; kk < 2; ++kk) { \
                const int off = row * 64 + ((kk * 32 + quad * 8) ^ ((row & 7) << 3)); \
                f1[n][kk] = *(const bf16x8*)&B1s[B][off]; \
                f3[n][kk] = *(const bf16x8*)&B3s[B][off]; \
            } \
        } \
        _Pragma("unroll") \
        for (int m = 0; m < 2; ++m) \
            _Pragma("unroll") \
            for (int n = 0; n < 2; ++n) \
                _Pragma("unroll") \
                for (int kk = 0; kk < 2; ++kk) { \
                    acc1[m][n] = __builtin_amdgcn_mfma_f32_16x16x32_bf16(afr[m][kk], f1[n][kk], acc1[m][n], 0, 0, 0); \
                    acc3[m][n] = __builtin_amdgcn_mfma_f32_16x16x32_bf16(afr[m][kk], f3[n][kk], acc3[m][n], 0, 0, 0); \
                } \
    } while (0)

    uint4 s0_a0, s0_a1; float4 s0_b1a, s0_b1b, s0_b3a, s0_b3b;
    uint4 s1_a0, s1_a1; float4 s1_b1a, s1_b1b, s1_b3a, s1_b3b;

    const int NK = H_DIM / 64;   // 16 (even)
    // prologue: tile0 -> buf0; tile1 in-flight in s1
    G1_LOAD(s0, 0);
    G1_STORE(s0, 0);
    G1_LOAD(s1, 64);
    SYNC_RAW();

    for (int ks = 0; ks < NK; ks += 2) {
        { const int k2 = (ks + 2 < NK) ? (ks + 2) * 64 : 0; G1_LOAD(s0, k2); }
        G1_COMPUTE(0);
        G1_STORE(s1, 1);                 // tile ks+1 -> buf1 (compiler waits counted vmcnt)
        SYNC_RAW();
        { const int k3 = (ks + 3 < NK) ? (ks + 3) * 64 : 0; G1_LOAD(s1, k3); }
        G1_COMPUTE(1);
        G1_STORE(s0, 0);                 // tile ks+2 -> buf0
        SYNC_RAW();
    }
#undef G1_LOAD
#undef G1_STORE
#undef G1_COMPUTE

    // epilogue: silu(h1)*h3 -> act (bf16). C/D layout: row=quad*4+reg, col=lane&15 (m89-verified)
    const int opad = meta->offs[e];
    #pragma unroll
    for (int m = 0; m < 2; ++m)
        #pragma unroll
        for (int n = 0; n < 2; ++n)
            #pragma unroll
            for (int rr = 0; rr < 4; ++rr) {
                const float v1 = acc1[m][n][rr];
                const float v3 = acc3[m][n][rr];
                const float s = v1 / (1.f + __expf(-v1)) * v3;
                const int row = opad + mt * 128 + mbase + m * 16 + quad * 4 + rr;
                const int col = it * 64 + nbase + n * 16 + l15;
                act[(size_t)row * I_DIM + col] = f2b(s);
            }
}

// ---------------- GEMM2: ybuf[kb] = act @ w2^T (partial over K), plain stores ----------------
// grid: (H/64, E, maxMTiles*KSPLIT), block 512. Same pipelined structure as gemm1.
__launch_bounds__(512, 4)
__global__ void gemm2_kernel(const unsigned short* __restrict__ act,
                             const float* __restrict__ w2,
                             const Meta* __restrict__ meta,
                             float* __restrict__ ybuf) {
    const int e = blockIdx.y;
    const int mt = blockIdx.z >> 1;     // KSPLIT == 2
    const int kb = blockIdx.z & 1;
    if (mt >= meta->tiles[e]) return;
    const int it = blockIdx.x;
    const int tid = threadIdx.x;
    const int opad = meta->offs[e];

    __shared__ __align__(16) unsigned short As[2][128 * 64];   // 2 x 16 KB
    __shared__ __align__(16) unsigned short Bs[2][64 * 64];    // 2 x 8 KB

    const int srow = tid >> 3, ssub = tid & 7;
    const int kbase = kb * (K2_STEPS * 64);                    // kb*1408
    const unsigned short* ap0 = act + (size_t)(opad + mt * 128 + srow) * I_DIM + kbase + ssub * 8;
    const unsigned short* ap1 = ap0 + (size_t)64 * I_DIM;
    const int scol = (ssub * 8) ^ ((srow & 7) << 3);
    const int aoff0 = srow * 64 + scol;
    const int aoff1 = (64 + srow) * 64 + scol;
    const int boff  = srow * 64 + scol;

    const float* bp = w2 + (size_t)e * H_DIM * I_DIM + (size_t)(it * 64 + srow) * I_DIM + kbase + ssub * 8;

    const int wave = tid >> 6, lane = tid & 63;
    const int quad = lane >> 4, l15 = lane & 15;
    const int mbase = (wave >> 1) * 32;
    const int nbase = (wave & 1) * 32;

    f32x4 acc[2][2];
    #pragma unroll
    for (int m = 0; m < 2; ++m)
        #pragma unroll
        for (int n = 0; n < 2; ++n) acc[m][n] = (f32x4){0.f, 0.f, 0.f, 0.f};

#define G2_LOAD(S, koff) do { \
        S##_a0 = *(const uint4*)(ap0 + (koff));  S##_a1 = *(const uint4*)(ap1 + (koff)); \
        S##_ba = *(const float4*)(bp + (koff));  S##_bb = *(const float4*)(bp + (koff) + 4); \
    } while (0)

#define G2_STORE(S, B) do { \
        *(uint4*)&As[B][aoff0] = S##_a0; \
        *(uint4*)&As[B][aoff1] = S##_a1; \
        *(uint4*)&Bs[B][boff]  = pack8(S##_ba, S##_bb); \
    } while (0)

#define G2_COMPUTE(B) do { \
        bf16x8 afr[2][2], bfr[2][2]; \
        _Pragma("unroll") \
        for (int m = 0; m < 2; ++m) { \
            const int row = mbase + m * 16 + l15; \
            _Pragma("unroll") \
            for (int kk = 0; kk < 2; ++kk) \
                afr[m][kk] = *(const bf16x8*)&As[B][row * 64 + ((kk * 32 + quad * 8) ^ ((row & 7) << 3))]; \
        } \
        _Pragma("unroll") \
        for (int n = 0; n < 2; ++n) { \
            const int row = nbase + n * 16 + l15; \
            _Pragma("unroll") \
            for (int kk = 0; kk < 2; ++kk) \
                bfr[n][kk] = *(const bf16x8*)&Bs[B][row * 64 + ((kk * 32 + quad * 8) ^ ((row & 7) << 3))]; \
        } \
        _Pragma("unroll") \
        for (int m = 0; m < 2; ++m) \
            _Pragma("unroll") \
            for (int n = 0; n < 2; ++n) \
                _Pragma("unroll") \
                for (int kk = 0; kk < 2; ++kk) \
                    acc[m][n] = __builtin_amdgcn_mfma_f32_16x16x32_bf16(afr[m][kk], bfr[n][kk], acc[m][n], 0, 0, 0); \
    } while (0)

    uint4 s0_a0, s0_a1; float4 s0_ba, s0_bb;
    uint4 s1_a0, s1_a1; float4 s1_ba, s1_bb;

    // prologue
    G2_LOAD(s0, 0);
    G2_STORE(s0, 0);
    G2_LOAD(s1, 64);
    SYNC_RAW();

    for (int ks = 0; ks < K2_STEPS; ks += 2) {   // 22 (even)
        { const int k2 = (ks + 2 < K2_STEPS) ? (ks + 2) * 64 : 0; G2_LOAD(s0, k2); }
        G2_COMPUTE(0);
        G2_STORE(s1, 1);
        SYNC_RAW();
        { const int k3 = (ks + 3 < K2_STEPS) ? (ks + 3) * 64 : 0; G2_LOAD(s1, k3); }
        G2_COMPUTE(1);
        G2_STORE(s0, 0);
        SYNC_RAW();
    }
#undef G2_LOAD
#undef G2_STORE
#undef G2_COMPUTE

    // epilogue: plain stores of fp32 partials (no atomics); padded rows written harmlessly
    float* yb = ybuf + (size_t)kb * ((size_t)MAXROWS * H_DIM);
    #pragma unroll
    for (int m = 0; m < 2; ++m)
        #pragma unroll
        for (int rr = 0; rr < 4; ++rr) {
            const int grow = opad + mt * 128 + mbase + m * 16 + quad * 4 + rr;
            #pragma unroll
            for (int n = 0; n < 2; ++n) {
                const int col = it * 64 + nbase + n * 16 + l15;
                yb[(size_t)grow * H_DIM + col] = acc[m][n][rr];
            }
        }
}

// ---------------- combine: out[t] = g0*(y[0][r0]+y[1][r0]) + g1*(y[0][r1]+y[1][r1]) ----------------
__global__ void combine_kernel(const float* __restrict__ ybuf,
                               const int4* __restrict__ comb,
                               float* __restrict__ out) {
    const int t = blockIdx.x;
    const int c = threadIdx.x;            // float4 column group, 256 per row
    const int4 cb = comb[t];
    const float g0 = __int_as_float(cb.z), g1 = __int_as_float(cb.w);
    const size_t sp = (size_t)MAXROWS * H_DIM;
    const float4 a = ((const float4*)(ybuf + (size_t)cb.x * H_DIM))[c];
    const float4 b = ((const float4*)(ybuf + sp + (size_t)cb.x * H_DIM))[c];
    const float4 d = ((const float4*)(ybuf + (size_t)cb.y * H_DIM))[c];
    const float4 f = ((const float4*)(ybuf + sp + (size_t)cb.y * H_DIM))[c];
    float4 o;
    o.x = g0 * (a.x + b.x) + g1 * (d.x + f.x);
    o.y = g0 * (a.y + b.y) + g1 * (d.y + f.y);
    o.z = g0 * (a.z + b.z) + g1 * (d.z + f.z);
    o.w = g0 * (a.w + b.w) + g1 * (d.w + f.w);
    ((float4*)(out + (size_t)t * H_DIM))[c] = o;
}

extern "C" void kernel_launch(void* const* d_in, const int* in_sizes, int n_in,
                              void* d_out, int out_size, void* d_ws, size_t ws_size,
                              hipStream_t stream) {
    const float* x      = (const float*)d_in[0];
    const float* logits = (const float*)d_in[1];
    const float* w1     = (const float*)d_in[2];
    const float* w3     = (const float*)d_in[3];
    const float* w2     = (const float*)d_in[4];
    float* out = (float*)d_out;

    char* ws = (char*)d_ws;
    int*   tok  = (int*)ws;                                   // 8*1024 ints (32 KB)
    Meta*  meta = (Meta*)(ws + 65536);
    int4*  comb = (int4*)(ws + 69632);                        // 1024 * 16 B
    unsigned short* xb  = (unsigned short*)(ws + 131072);     // 1M bf16 (2 MB)
    unsigned short* act = (unsigned short*)(ws + 2228224);    // 3072 x 2816 bf16 (17.3 MB)
    float* ybuf = (float*)(ws + 19529728);                    // 2 x 3072 x 1024 fp32 (25.2 MB)

    route_kernel<<<1, 1024, 0, stream>>>(logits, tok, comb, meta);
    cvt_x_kernel<<<T_TOK * H_DIM / 4 / 256, 256, 0, stream>>>(x, xb);
    gemm1_kernel<<<dim3(I_DIM / 64, E_NUM, 8), 512, 0, stream>>>(xb, w1, w3, tok, meta, act);
    gemm2_kernel<<<dim3(H_DIM / 64, E_NUM, 8 * KSPLIT), 512, 0, stream>>>(act, w2, meta, ybuf);
    combine_kernel<<<T_TOK, 256, 0, stream>>>(ybuf, comb, out);
}